// Round 2
// baseline (135.103 us; speedup 1.0000x reference)
//
#include <hip/hip_runtime.h>

// Path signature depth-3 for path (N=32, L=128, C=48) fp32.
//
// Math: with increments v_t = p[t+1]-p[t], prefix P_t = p[t]-p[0] (telescoped),
//   G_t[i] = P_t[i] + v_t[i]/2
//   R_t[i] = P_t[i]/2 + v_t[i]/6
//   S1[i]    = P_T[i]
//   S2[i,j]  = sum_t G_t[i] v_t[j]
//   S3[i,j,k]= sum_t ( A2prev_t[i,j] + R_t[i] v_t[j] ) * v_t[k]
// where A2prev_t[i,j] is the running S2 prefix (register-carried over t).
//
// R2 change: k-dimension split 4-ways (12 k per thread) to lift occupancy
// 4.5 -> 18 waves/CU. R1 showed VALUBusy 11.9% ~= occupancy bound 10.5%:
// the kernel was resident-wave starved, not pipe-limited.

#define N_BATCH 32
#define LPATH   128
#define T_STEPS 127
#define C       48
#define C2      2304
#define C3      110592
#define OUT_PER_N (C + C2 + C3)      // 112944
#define PATH_PER_N (LPATH * C)       // 6144
#define TC (T_STEPS * C)             // 6096
#define WAVES_PER_BATCH (C2 / 64)    // 36
#define SPLITK 4
#define KPER   12                    // 48 / SPLITK

// ---------------- prep: v, G, R into ws; S1 into out ----------------
__global__ void sig_prep(const float* __restrict__ path,
                         float* __restrict__ ws,
                         float* __restrict__ out) {
    const int total = N_BATCH * TC;
    int e = blockIdx.x * blockDim.x + threadIdx.x;
    if (e < total) {
        int n = e / TC;
        int r = e - n * TC;
        int t = r / C;
        int i = r - t * C;
        const float* p = path + n * PATH_PER_N;
        float pt  = p[t * C + i];
        float pt1 = p[(t + 1) * C + i];
        float p0  = p[i];
        float v = pt1 - pt;
        float P = pt - p0;
        ws[e]             = v;                            // v
        ws[total + e]     = P + 0.5f * v;                 // G
        ws[2 * total + e] = 0.5f * P + v * (1.0f / 6.0f); // R
    }
    if (e < N_BATCH * C) {
        int n = e / C;
        int i = e - n * C;
        const float* p = path + n * PATH_PER_N;
        out[n * OUT_PER_N + i] = p[(LPATH - 1) * C + i] - p[i];  // S1
    }
}

// ---------------- main: one thread per (i,j, k-chunk) ----------------
// Block = 256 threads = 4 waves; all 4 waves cover the same 64 ij rows,
// one k-chunk of 12 each. Grid = 32 batches * 36 ij-groups = 1152 blocks
// -> 4608 waves -> 18 waves/CU.
__global__ __launch_bounds__(256) void sig_main(const float* __restrict__ ws,
                                                float* __restrict__ out) {
    const int total = N_BATCH * TC;
    int bid = blockIdx.x;
    int n = bid / WAVES_PER_BATCH;
    int g = bid - n * WAVES_PER_BATCH;
    int lane = threadIdx.x & 63;
    int kc   = threadIdx.x >> 6;          // 0..3
    int ij = g * 64 + lane;               // 0..2303
    int i = ij / C;
    int j = ij - i * C;

    const float* __restrict__ v = ws + n * TC;
    const float* __restrict__ G = ws + total + n * TC;
    const float* __restrict__ R = ws + 2 * total + n * TC;
    const float* __restrict__ vk = v + kc * KPER;   // this thread's k-chunk base

    float s3[KPER];
    #pragma unroll
    for (int k = 0; k < KPER; ++k) s3[k] = 0.0f;
    float a2 = 0.0f;

    #pragma unroll 2
    for (int t = 0; t < T_STEPS; ++t) {
        const float4* vk4 = (const float4*)(vk + t * C);  // 16B aligned (48B offset per kc)
        float4 va = vk4[0];
        float4 vb = vk4[1];
        float4 vc = vk4[2];
        float vj = v[t * C + j];
        float Gt = G[t * C + i];
        float Rt = R[t * C + i];
        float b = a2 + Rt * vj;   // uses A2prev (pre-update)
        a2 += Gt * vj;
        s3[0]  += b * va.x;  s3[1]  += b * va.y;  s3[2]  += b * va.z;  s3[3]  += b * va.w;
        s3[4]  += b * vb.x;  s3[5]  += b * vb.y;  s3[6]  += b * vb.z;  s3[7]  += b * vb.w;
        s3[8]  += b * vc.x;  s3[9]  += b * vc.y;  s3[10] += b * vc.z;  s3[11] += b * vc.w;
    }

    // S2: final prefix value (only one k-chunk writes)
    if (kc == 0)
        out[n * OUT_PER_N + C + ij] = a2;

    // S3: this thread's 12 consecutive floats, 16B-aligned
    float4* dst = (float4*)(out + n * OUT_PER_N + C + C2 + (long)ij * C + kc * KPER);
    dst[0] = make_float4(s3[0], s3[1], s3[2],  s3[3]);
    dst[1] = make_float4(s3[4], s3[5], s3[6],  s3[7]);
    dst[2] = make_float4(s3[8], s3[9], s3[10], s3[11]);
}

extern "C" void kernel_launch(void* const* d_in, const int* in_sizes, int n_in,
                              void* d_out, int out_size, void* d_ws, size_t ws_size,
                              hipStream_t stream) {
    const float* path = (const float*)d_in[0];
    float* out = (float*)d_out;
    float* ws = (float*)d_ws;   // needs 3 * 32*127*48 * 4 B = 2.34 MB

    int prep_threads = N_BATCH * TC;                      // 195072
    int prep_blocks = (prep_threads + 255) / 256;         // 762
    sig_prep<<<prep_blocks, 256, 0, stream>>>(path, ws, out);

    sig_main<<<N_BATCH * WAVES_PER_BATCH, 256, 0, stream>>>(ws, out);
}

// Round 3
// 128.929 us; speedup vs baseline: 1.0479x; 1.0479x over previous
//
#include <hip/hip_runtime.h>

// Path signature depth-3 for path (N=32, L=128, C=48) fp32.
//
// Math: v_t = p[t+1]-p[t], P_t = p[t]-p[0],
//   G_t[i] = P_t[i] + v_t[i]/2,  R_t[i] = P_t[i]/2 + v_t[i]/6
//   S1 = P_T;  S2[i,j] = sum_t G_t[i] v_t[j]
//   S3[i,j,k] = sum_t ( A2prev_t[i,j] + R_t[i] v_t[j] ) v_t[k],
// with A2prev the register-carried running S2 prefix.
//
// R3 change: R2 post-mortem showed per-iter ~1000+ cyc stalls. Theory: the
// wave-uniform v-row float4 loads were lowered to s_load (SGPR_Count 80->32
// matches), and SMEM misses serialize at lgkmcnt(0) each iteration with no
// pipelining. Fix: LANE-ROTATED chunk loads (lane l reads chunk (c+l)%6) so
// the loads are per-lane VMEM with real MLP; accumulators live in rotated
// order and are un-rotated at store. SPLITK=2 + explicit 2-stage ping-pong
// software pipeline (127 = 1 + 63*2, no guards).

#define N_BATCH 32
#define LPATH   128
#define T_STEPS 127
#define C       48
#define C2      2304
#define C3      110592
#define OUT_PER_N (C + C2 + C3)      // 112944
#define PATH_PER_N (LPATH * C)       // 6144
#define TC (T_STEPS * C)             // 6096
#define WAVES_PER_BATCH (C2 / 64)    // 36
#define SPLITK 2
#define KPER   24                    // 48 / SPLITK
#define NCH    6                     // float4 chunks per thread

// ---------------- prep: v, G, R into ws; S1 into out ----------------
__global__ void sig_prep(const float* __restrict__ path,
                         float* __restrict__ ws,
                         float* __restrict__ out) {
    const int total = N_BATCH * TC;
    int e = blockIdx.x * blockDim.x + threadIdx.x;
    if (e < total) {
        int n = e / TC;
        int r = e - n * TC;
        int t = r / C;
        int i = r - t * C;
        const float* p = path + n * PATH_PER_N;
        float pt  = p[t * C + i];
        float pt1 = p[(t + 1) * C + i];
        float p0  = p[i];
        float v = pt1 - pt;
        float P = pt - p0;
        ws[e]             = v;                            // v
        ws[total + e]     = P + 0.5f * v;                 // G
        ws[2 * total + e] = 0.5f * P + v * (1.0f / 6.0f); // R
    }
    if (e < N_BATCH * C) {
        int n = e / C;
        int i = e - n * C;
        const float* p = path + n * PATH_PER_N;
        out[n * OUT_PER_N + i] = p[(LPATH - 1) * C + i] - p[i];  // S1
    }
}

// ---------------- main: thread = (ij row, k-half), lane-rotated loads ----
// Block = 128 (2 waves: kc 0/1 over same 64 ij rows). Grid = 32*36 = 1152
// blocks -> 2304 waves.
__global__ __launch_bounds__(128) void sig_main(const float* __restrict__ ws,
                                                float* __restrict__ out) {
    const int total = N_BATCH * TC;
    int bid = blockIdx.x;
    int n = bid / WAVES_PER_BATCH;
    int g = bid - n * WAVES_PER_BATCH;
    int lane = threadIdx.x & 63;
    int kc   = threadIdx.x >> 6;          // 0..1
    int ij = g * 64 + lane;               // 0..2303
    int i = ij / C;
    int j = ij - i * C;

    const float* __restrict__ v = ws + n * TC;
    const float* __restrict__ G = ws + total + n * TC;
    const float* __restrict__ R = ws + 2 * total + n * TC;

    // per-lane rotated chunk indices: lane l touches chunk (c+l)%6 at step c
    int rot[NCH];
    #pragma unroll
    for (int c = 0; c < NCH; ++c) rot[c] = (c + lane) % NCH;

    const float4* __restrict__ pv = (const float4*)(v + kc * KPER); // uniform base
    const float* __restrict__ pvj = v + j;                           // per-lane
    const float* __restrict__ pGi = G + i;
    const float* __restrict__ pRi = R + i;

    float s3[KPER];
    #pragma unroll
    for (int k = 0; k < KPER; ++k) s3[k] = 0.0f;
    float a2 = 0.0f;

    float4 bufv[2][NCH];
    float  bufj[2], bufG[2], bufR[2];

#define LOADSTAGE(s, tt) do {                                         \
    const float4* p_ = pv + (tt) * (C / 4);                           \
    _Pragma("unroll")                                                 \
    for (int c = 0; c < NCH; ++c) bufv[s][c] = p_[rot[c]];            \
    bufj[s] = pvj[(tt) * C];                                          \
    bufG[s] = pGi[(tt) * C];                                          \
    bufR[s] = pRi[(tt) * C];                                          \
} while (0)

#define COMPUTESTAGE(s) do {                                          \
    float b_ = a2 + bufR[s] * bufj[s];                                \
    a2 += bufG[s] * bufj[s];                                          \
    _Pragma("unroll")                                                 \
    for (int c = 0; c < NCH; ++c) {                                   \
        s3[4*c+0] += b_ * bufv[s][c].x;                               \
        s3[4*c+1] += b_ * bufv[s][c].y;                               \
        s3[4*c+2] += b_ * bufv[s][c].z;                               \
        s3[4*c+3] += b_ * bufv[s][c].w;                               \
    }                                                                 \
} while (0)

    LOADSTAGE(0, 0);
    #pragma unroll 1
    for (int t = 0; t < T_STEPS - 1; t += 2) {
        LOADSTAGE(1, t + 1);
        COMPUTESTAGE(0);
        LOADSTAGE(0, t + 2);      // t+2 <= 126 always (t <= 124)
        COMPUTESTAGE(1);
    }
    COMPUTESTAGE(0);              // t = 126

    // S2: final prefix value (one k-half writes)
    if (kc == 0)
        out[n * OUT_PER_N + C + ij] = a2;

    // S3: un-rotate and store this thread's 24 floats (16B aligned)
    float4* dst = (float4*)(out + n * OUT_PER_N + C + C2 + (long)ij * C + kc * KPER);
    #pragma unroll
    for (int c = 0; c < NCH; ++c)
        dst[rot[c]] = make_float4(s3[4*c+0], s3[4*c+1], s3[4*c+2], s3[4*c+3]);
}

extern "C" void kernel_launch(void* const* d_in, const int* in_sizes, int n_in,
                              void* d_out, int out_size, void* d_ws, size_t ws_size,
                              hipStream_t stream) {
    const float* path = (const float*)d_in[0];
    float* out = (float*)d_out;
    float* ws = (float*)d_ws;   // needs 3 * 32*127*48 * 4 B = 2.34 MB

    int prep_threads = N_BATCH * TC;                      // 195072
    int prep_blocks = (prep_threads + 255) / 256;         // 762
    sig_prep<<<prep_blocks, 256, 0, stream>>>(path, ws, out);

    sig_main<<<N_BATCH * WAVES_PER_BATCH, 128, 0, stream>>>(ws, out);
}

// Round 4
// 76.142 us; speedup vs baseline: 1.7744x; 1.6933x over previous
//
#include <hip/hip_runtime.h>

// Path signature depth-3, path (N=32, L=128, C=48) fp32 — fused single kernel.
//
// Math: v_t = p[t+1]-p[t], P_t[i] = sum_{s<t} v_s[i] (running register),
//   G_t[i] = P_t[i] + v_t[i]/2,  R_t[i] = P_t[i]/2 + v_t[i]/6
//   S1 = p[127]-p[0]
//   S2[i,j]   = sum_t G_t[i] v_t[j]            (register prefix a2)
//   S3[i,j,k] = sum_t (a2prefix_t[i,j] + R_t[i] v_t[j]) v_t[k]
//
// R4 changes (R3 post-mortem: L1 return-BW bound, ~7 KB L1 traffic per
// wave-iter for 26 FMAs; 2 GB/256 CU/64 Bcyc = 52 us ~ measured 78 us):
//  1. v staged in LDS (24.4 KB) — broadcast reads are ~free there.
//  2. Register blocking: thread = (i, 4 j, 12 k) -> 48 acc, 56 FMA/iter
//     vs 5 LDS reads -> VALU-bound (~126 cyc/iter predicted).
//  3. t-split x2 inside block (wave0: t<64, wave1: t>=64) with exact
//     prefix fixup S3 += a2_half0 * W, W = p[127]-p[64]; LDS exchange.
//  4. prep kernel + ws eliminated; G,R derived from running Pi via one
//     broadcast ds_read_b32.

#define N_BATCH 32
#define LPATH   128
#define T_STEPS 127
#define C       48
#define C2      2304
#define C3      110592
#define OUT_PER_N (C + C2 + C3)      // 112944
#define PATH_PER_N (LPATH * C)       // 6144
#define GROUPS_PER_BATCH 36          // 2304 (i,jg,kc) units / 64 lanes
#define THALF 64

__global__ __launch_bounds__(128) void sig_fused(const float* __restrict__ path,
                                                 float* __restrict__ out) {
    __shared__ float lds[T_STEPS * C];   // v matrix (24.4 KB); reduce buf after loop

    int bid = blockIdx.x;
    int n = bid / GROUPS_PER_BATCH;
    int g = bid - n * GROUPS_PER_BATCH;
    int tid = threadIdx.x;
    int w = tid >> 6;                    // 0: t<64, 1: t>=64
    int lane = tid & 63;

    const float* __restrict__ pb = path + n * PATH_PER_N;

    // ---- stage v = diff(p) into LDS (coalesced float4) ----
    {
        const float4* p4 = (const float4*)pb;
        float4* v4 = (float4*)lds;
        #pragma unroll
        for (int c = 0; c < 12; ++c) {
            int idx = tid + 128 * c;
            if (idx < (T_STEPS * C) / 4) {           // 1524
                float4 a = p4[idx];
                float4 b = p4[idx + 12];             // next path row (+48 floats)
                v4[idx] = make_float4(b.x - a.x, b.y - a.y, b.z - a.z, b.w - a.w);
            }
        }
    }
    __syncthreads();

    // unit U -> (i, jg, kc):  U = 48 i + 4 jg + kc
    int U = g * 64 + lane;
    int i = U / 48;
    int r = U - 48 * i;
    int jg = r >> 2;
    int kc = r & 3;

    float Pi = (w == 0) ? 0.0f : (pb[THALF * C + i] - pb[i]);
    float a2[4] = {0.f, 0.f, 0.f, 0.f};
    float s3[4][12];
    #pragma unroll
    for (int jj = 0; jj < 4; ++jj)
        #pragma unroll
        for (int c = 0; c < 12; ++c) s3[jj][c] = 0.f;

    int t0 = w ? THALF : 0;
    int t1 = w ? T_STEPS : THALF;

    #pragma unroll 2
    for (int t = t0; t < t1; ++t) {
        const float* base = lds + t * C;
        float4 vj = *(const float4*)(base + 4 * jg);       // per-lane j-chunk
        float4 k0 = *(const float4*)(base + kc * 12);      // broadcast k-chunk
        float4 k1 = *(const float4*)(base + kc * 12 + 4);
        float4 k2 = *(const float4*)(base + kc * 12 + 8);
        float vi = base[i];                                // broadcast
        float G = Pi + 0.5f * vi;
        float R = 0.5f * Pi + (1.0f / 6.0f) * vi;
        Pi += vi;
        float vja[4] = {vj.x, vj.y, vj.z, vj.w};
        #pragma unroll
        for (int jj = 0; jj < 4; ++jj) {
            float b = a2[jj] + R * vja[jj];
            a2[jj] += G * vja[jj];
            s3[jj][0]  += b * k0.x;  s3[jj][1]  += b * k0.y;
            s3[jj][2]  += b * k0.z;  s3[jj][3]  += b * k0.w;
            s3[jj][4]  += b * k1.x;  s3[jj][5]  += b * k1.y;
            s3[jj][6]  += b * k1.z;  s3[jj][7]  += b * k1.w;
            s3[jj][8]  += b * k2.x;  s3[jj][9]  += b * k2.y;
            s3[jj][10] += b * k2.z;  s3[jj][11] += b * k2.w;
        }
    }

    __syncthreads();      // all v-reads done; lds becomes the reduce buffer

    float* red = lds;     // stride 56 floats/lane (4-way bank alias, aligned)
    if (w == 0) {
        float* dst = red + lane * 56;
        #pragma unroll
        for (int jj = 0; jj < 4; ++jj)
            #pragma unroll
            for (int c = 0; c < 12; c += 4)
                *(float4*)(dst + jj * 12 + c) =
                    make_float4(s3[jj][c], s3[jj][c+1], s3[jj][c+2], s3[jj][c+3]);
        *(float4*)(dst + 48) = make_float4(a2[0], a2[1], a2[2], a2[3]);
    }
    __syncthreads();

    if (w == 1) {
        const float* src = red + lane * 56;
        // W[c] = p[127][kc*12+c] - p[64][kc*12+c]
        float W[12];
        #pragma unroll
        for (int c = 0; c < 12; c += 4) {
            float4 pe = *(const float4*)(pb + 127 * C + kc * 12 + c);
            float4 ph = *(const float4*)(pb + THALF * C + kc * 12 + c);
            W[c]   = pe.x - ph.x;  W[c+1] = pe.y - ph.y;
            W[c+2] = pe.z - ph.z;  W[c+3] = pe.w - ph.w;
        }
        float4 a20 = *(const float4*)(src + 48);
        float a20a[4] = {a20.x, a20.y, a20.z, a20.w};

        int ij0 = 48 * i + 4 * jg;
        // S2 (both halves combined)
        *(float4*)(out + (long)n * OUT_PER_N + C + ij0) =
            make_float4(a20a[0] + a2[0], a20a[1] + a2[1],
                        a20a[2] + a2[2], a20a[3] + a2[3]);
        // S3
        #pragma unroll
        for (int jj = 0; jj < 4; ++jj) {
            float* dst = out + (long)n * OUT_PER_N + C + C2
                       + (long)(ij0 + jj) * C + kc * 12;
            #pragma unroll
            for (int c = 0; c < 12; c += 4) {
                float4 s0 = *(const float4*)(src + jj * 12 + c);
                dst[0 + c]     = s0.x + s3[jj][c]   + a20a[jj] * W[c];
                dst[1 + c]     = s0.y + s3[jj][c+1] + a20a[jj] * W[c+1];
                dst[2 + c]     = s0.z + s3[jj][c+2] + a20a[jj] * W[c+2];
                dst[3 + c]     = s0.w + s3[jj][c+3] + a20a[jj] * W[c+3];
            }
        }
    }

    // S1 (once per batch)
    if (w == 0 && g == 0 && lane < 48) {
        out[(long)n * OUT_PER_N + lane] = pb[127 * C + lane] - pb[lane];
    }
}

extern "C" void kernel_launch(void* const* d_in, const int* in_sizes, int n_in,
                              void* d_out, int out_size, void* d_ws, size_t ws_size,
                              hipStream_t stream) {
    const float* path = (const float*)d_in[0];
    float* out = (float*)d_out;
    (void)d_ws; (void)ws_size;

    sig_fused<<<N_BATCH * GROUPS_PER_BATCH, 128, 0, stream>>>(path, out);
}